// Round 1
// baseline (843.850 us; speedup 1.0000x reference)
//
#include <hip/hip_runtime.h>
#include <hip/hip_bf16.h>

// Elementwise SiLU: out[i] = x[i] * sigmoid(x[i]) = x[i] / (1 + exp(-x[i]))
// fp32 in / fp32 out, N = 8*8192*2048 = 134217728 (divisible by 4).
// Pure streaming, memory-bound: float4 vectorized grid-stride loop.

__device__ __forceinline__ float silu(float x) {
    // x / (1 + e^-x): matches x*sigmoid(x) in fp32 for all finite x,
    // including large |x| (exp overflow -> inf -> quotient 0, correct limit).
    return x / (1.0f + expf(-x));
}

__global__ void __launch_bounds__(256) silu_f32x4_kernel(
    const float4* __restrict__ in, float4* __restrict__ out, int n4) {
    int i = blockIdx.x * blockDim.x + threadIdx.x;
    int stride = gridDim.x * blockDim.x;
    for (; i < n4; i += stride) {
        float4 v = in[i];
        v.x = silu(v.x);
        v.y = silu(v.y);
        v.z = silu(v.z);
        v.w = silu(v.w);
        out[i] = v;
    }
}

extern "C" void kernel_launch(void* const* d_in, const int* in_sizes, int n_in,
                              void* d_out, int out_size, void* d_ws, size_t ws_size,
                              hipStream_t stream) {
    const float4* in = (const float4*)d_in[0];
    float4* out = (float4*)d_out;
    int n = in_sizes[0];          // 134217728
    int n4 = n >> 2;              // 33554432 float4 elements

    const int block = 256;
    // Memory-bound streaming: cap at 256 CU * 8 blocks/CU = 2048, grid-stride.
    int grid = (n4 + block - 1) / block;
    if (grid > 2048) grid = 2048;

    silu_f32x4_kernel<<<grid, block, 0, stream>>>(in, out, n4);
}